// Round 8
// baseline (311.259 us; speedup 1.0000x reference)
//
#include <hip/hip_runtime.h>

// Problem constants (B=32, T=4096, D=256, A=128, window=64)
#define TT 4096
#define DD 256
#define AA 128
#define WIN 64

typedef short bf16x8 __attribute__((ext_vector_type(8)));
typedef float f32x4 __attribute__((ext_vector_type(4)));
typedef unsigned int u32x4 __attribute__((ext_vector_type(4)));

__device__ __forceinline__ unsigned short f2bf(float f) {
    unsigned int u = __builtin_bit_cast(unsigned int, f);
    u += 0x7FFFu + ((u >> 16) & 1u);   // RTNE
    return (unsigned short)(u >> 16);
}

// packed f32x2 -> bf16x2 (RTNE), element 0 = lo
__device__ __forceinline__ unsigned int cvt_pk_bf16(float lo, float hi) {
    unsigned int r;
    asm("v_cvt_pk_bf16_f32 %0, %1, %2" : "=v"(r) : "v"(lo), "v"(hi));
    return r;
}

// ---------------- prep: Wp fp32 -> bf16 (64 KiB, L2-resident) ----------------
__global__ __launch_bounds__(256) void prep_wp(const float* __restrict__ Wp,
                                               unsigned short* __restrict__ wpb) {
    int i = blockIdx.x * 256 + threadIdx.x;   // 32768 total
    wpb[i] = f2bf(Wp[i]);
}

// ---------------- fused v7: gate + stream, register cs-history ---------------
// out[t] = (cs[t]-cs[t-64])/(Sg). Thread owns column d: cs[t-64] is its OWN
// value 2 subtiles ago -> 64-deep register ring (hA/hB, parity-static index).
// Stream reads x ONLY from the current LDS tile (lag-0); zero global x reads.
// g recomputed per-thread from transposed psum (broadcast b128) -> no 3rd
// barrier. 2-deep x ring (64 KiB) -> 2 blocks/CU; NT stores for out; barrier1
// waits vmcnt(32) so NT stores stay in flight, only stage loads drain.
#define SROWS 32
#define TC    256
#define NU    ((TC + WIN) / SROWS)   // 10 subtiles incl. 2 halo
#define NCHK  (TT / TC)              // 16 chunks per batch row

__global__ __launch_bounds__(256, 2) void fused_kernel(
        const float* __restrict__ x, const unsigned short* __restrict__ wpb,
        const float* __restrict__ bp, const float* __restrict__ Wg,
        float* __restrict__ out) {
    __shared__ __align__(16) float xs[2][SROWS * DD];   // 64 KiB ring
    __shared__ float gbuf[4][SROWS];                    // g ring (for Sg gold)
    __shared__ __align__(16) float psv[SROWS][4];       // psum, [row][wave]
    const int tid  = threadIdx.x;
    const int lane = tid & 63;
    const int wave = tid >> 6;
    const int quad = lane >> 4;
    const int nrow = lane & 15;
    const int sw   = nrow & 7;          // row&7 == nrow&7 (mt*16 ≡ 0 mod 8)
    const int b     = blockIdx.x >> 4;          // NCHK = 16
    const int chunk = blockIdx.x & (NCHK - 1);
    const long t0   = (long)chunk * TC;
    const float* xb = x   + (size_t)b * TT * DD;
    float*       ob = out + (size_t)b * TT * DD;

    // B fragments: wave covers n in [wave*32, wave*32+32)
    bf16x8 bfrag[2][8];
    float bpv[2], wgv[2];
#pragma unroll
    for (int nt = 0; nt < 2; ++nt) {
        int n = wave * 32 + nt * 16 + nrow;
        bpv[nt] = bp[n];
        wgv[nt] = Wg[n];
#pragma unroll
        for (int k0 = 0; k0 < 8; ++k0)
            bfrag[nt][k0] = *reinterpret_cast<const bf16x8*>(
                wpb + n * DD + k0 * 32 + quad * 8);
    }

    // stage subtile su into ring slot su&1: 8 global_load_lds dwordx4 / wave.
    // LDS dest linear (row r, granule lane); global source granule lane^(r&7).
    auto stage = [&](int su) {
        const int nb = su & 1;
        const long r0 = t0 - WIN + (long)su * SROWS;
#pragma unroll
        for (int j = 0; j < 8; ++j) {
            int r = wave * 8 + j;
            long row = r0 + r;
            row = row < 0 ? 0 : row;          // t0=0 halo clamp (g=0 kills it)
            const float* gp = xb + row * DD + ((lane ^ (r & 7)) << 2);
            __builtin_amdgcn_global_load_lds(
                (const __attribute__((address_space(1))) void*)gp,
                (__attribute__((address_space(3))) void*)&xs[nb][r * DD],
                16, 0, 0);
        }
    };

    float hA[SROWS], hB[SROWS];   // cs history: 64 steps, parity-split, static idx
    float cs = 0.f, Sg = 0.f;

    stage(0);

    // stream body: per-thread g recompute + cs recurrence + windowed output.
    // H = parity-selected history array; all indices compile-time constants.
#define SBODY(H)                                                              \
    _Pragma("unroll")                                                         \
    for (int tt = 0; tt < SROWS; ++tt) {                                      \
        long t = rbase + tt;                                                  \
        f32x4 ps = *reinterpret_cast<const f32x4*>(&psv[tt][0]);              \
        float ss = (ps[0] + ps[1]) + (ps[2] + ps[3]);                         \
        float gnew = __builtin_amdgcn_rcpf(1.0f + __expf(-ss));               \
        if (t < 0) gnew = 0.f;                                                \
        if (tid == tt) gbuf[u & 3][tt] = gnew;                                \
        int off = tt * DD + ((((tid >> 2) ^ (tt & 7)) << 2) | (tid & 3));     \
        cs += gnew * xt[off];                                                 \
        if (u >= 2) {                                                         \
            float gold = gbuf[(u + 2) & 3][tt];                               \
            Sg += gnew - gold;                                                \
            float h = H[tt];                                                  \
            H[tt] = cs;                                                       \
            float o = (cs - h) * __builtin_amdgcn_rcpf(Sg);                   \
            __builtin_nontemporal_store(o, &ob[t * DD + tid]);                \
        } else {                                                              \
            Sg += gnew;                                                       \
            H[tt] = cs;                                                       \
        }                                                                     \
    }

    for (int u = 0; u < NU; ++u) {
        // barrier1: stage(u) arrived (leave last iter's 32 NT stores in
        // flight); lgkmcnt(0) publishes last iter's gbuf/psv ds ops.
        if (u >= 3) asm volatile("s_waitcnt vmcnt(32) lgkmcnt(0)" ::: "memory");
        else        asm volatile("s_waitcnt vmcnt(0) lgkmcnt(0)"  ::: "memory");
        __builtin_amdgcn_sched_barrier(0);
        __builtin_amdgcn_s_barrier();        // stage(u) visible; slot (u+1)&1 free
        __builtin_amdgcn_sched_barrier(0);

        if (u + 1 < NU) stage(u + 1);        // prefetch, in flight all body

        // ---- gate MFMA on xs[u&1] ----
        const float* buf = xs[u & 1];
        f32x4 acc[2][2];
#pragma unroll
        for (int mt = 0; mt < 2; ++mt)
#pragma unroll
            for (int nt = 0; nt < 2; ++nt)
                acc[mt][nt] = (f32x4){0.f, 0.f, 0.f, 0.f};
#pragma unroll
        for (int k0 = 0; k0 < 8; ++k0) {
#pragma unroll
            for (int mt = 0; mt < 2; ++mt) {
                const float* rowp = buf + (mt * 16 + nrow) * DD;
                const int gidx = quad * 2 + k0 * 8;
                float4 f0 = *reinterpret_cast<const float4*>(rowp + (((gidx)     ^ sw) << 2));
                float4 f1 = *reinterpret_cast<const float4*>(rowp + (((gidx + 1) ^ sw) << 2));
                u32x4 w;
                w.x = cvt_pk_bf16(f0.x, f0.y);
                w.y = cvt_pk_bf16(f0.z, f0.w);
                w.z = cvt_pk_bf16(f1.x, f1.y);
                w.w = cvt_pk_bf16(f1.z, f1.w);
                bf16x8 af = __builtin_bit_cast(bf16x8, w);
                acc[mt][0] = __builtin_amdgcn_mfma_f32_16x16x32_bf16(af, bfrag[0][k0], acc[mt][0], 0, 0, 0);
                acc[mt][1] = __builtin_amdgcn_mfma_f32_16x16x32_bf16(af, bfrag[1][k0], acc[mt][1], 0, 0, 0);
            }
        }
        // epilogue: tanh -> *Wg -> partial row sums
        float p[2][4];
#pragma unroll
        for (int mt = 0; mt < 2; ++mt)
#pragma unroll
            for (int r = 0; r < 4; ++r) p[mt][r] = 0.f;
#pragma unroll
        for (int nt = 0; nt < 2; ++nt) {
#pragma unroll
            for (int mt = 0; mt < 2; ++mt) {
#pragma unroll
                for (int r = 0; r < 4; ++r) {
                    float pre = acc[mt][nt][r] + bpv[nt];
                    float e  = __expf(2.0f * pre);
                    float th = 1.0f - 2.0f * __builtin_amdgcn_rcpf(e + 1.0f);
                    p[mt][r] += th * wgv[nt];
                }
            }
        }
#pragma unroll
        for (int off = 1; off <= 8; off <<= 1)
#pragma unroll
            for (int mt = 0; mt < 2; ++mt)
#pragma unroll
                for (int r = 0; r < 4; ++r)
                    p[mt][r] += __shfl_xor(p[mt][r], off, 64);
        if (nrow == 0) {
#pragma unroll
            for (int mt = 0; mt < 2; ++mt)
#pragma unroll
                for (int r = 0; r < 4; ++r)
                    psv[mt * 16 + quad * 4 + r][wave] = p[mt][r];
        }

        asm volatile("s_waitcnt lgkmcnt(0)" ::: "memory");
        __builtin_amdgcn_sched_barrier(0);
        __builtin_amdgcn_s_barrier();        // psv visible
        __builtin_amdgcn_sched_barrier(0);

        // ---- stream (lag-0): g recompute + cs recurrence + output ----
        {
            const long rbase = t0 - WIN + (long)u * SROWS;
            const float* xt = xs[u & 1];
            if (u & 1) { SBODY(hB) } else { SBODY(hA) }
        }
        // stream's ds_reads of slot u&1 are fenced by next iter's
        // lgkmcnt(0)+barrier1 before stage(u+2) can overwrite it.
    }
#undef SBODY
}

extern "C" void kernel_launch(void* const* d_in, const int* in_sizes, int n_in,
                              void* d_out, int out_size, void* d_ws, size_t ws_size,
                              hipStream_t stream) {
    const float* x  = (const float*)d_in[0];
    const float* Wp = (const float*)d_in[1];
    const float* bp = (const float*)d_in[2];
    const float* Wg = (const float*)d_in[3];
    float* out = (float*)d_out;

    // ws layout: [0,64K) Wp bf16
    unsigned short* wpb = (unsigned short*)d_ws;

    prep_wp<<<AA * DD / 256, 256, 0, stream>>>(Wp, wpb);
    fused_kernel<<<32 * NCHK, 256, 0, stream>>>(x, wpb, bp, Wg, out);
}

// Round 9
// 287.686 us; speedup vs baseline: 1.0819x; 1.0819x over previous
//
#include <hip/hip_runtime.h>

// Problem constants (B=32, T=4096, D=256, A=128, window=64)
#define TT 4096
#define DD 256
#define AA 128
#define WIN 64

typedef short bf16x8 __attribute__((ext_vector_type(8)));
typedef float f32x4 __attribute__((ext_vector_type(4)));
typedef unsigned int u32x4 __attribute__((ext_vector_type(4)));

__device__ __forceinline__ unsigned short f2bf(float f) {
    unsigned int u = __builtin_bit_cast(unsigned int, f);
    u += 0x7FFFu + ((u >> 16) & 1u);   // RTNE
    return (unsigned short)(u >> 16);
}

// packed f32x2 -> bf16x2 (RTNE), element 0 = lo
__device__ __forceinline__ unsigned int cvt_pk_bf16(float lo, float hi) {
    unsigned int r;
    asm("v_cvt_pk_bf16_f32 %0, %1, %2" : "=v"(r) : "v"(lo), "v"(hi));
    return r;
}

// ---------------- prep: Wp fp32 -> bf16 (64 KiB, L2-resident) ----------------
__global__ __launch_bounds__(256) void prep_wp(const float* __restrict__ Wp,
                                               unsigned short* __restrict__ wpb) {
    int i = blockIdx.x * 256 + threadIdx.x;   // 32768 total
    wpb[i] = f2bf(Wp[i]);
}

// ---------------- fused v8: v6 finalize + v7 register cs-history -------------
// out[t] = (cs[t]-cs[t-64])/Sg. Thread owns column d; cs[t-64] lives in a
// 64-deep register ring (hA/hB, parity-static index). Stream reads x ONLY from
// the current LDS tile; zero global x reads in stream. g computed ONCE per row
// (32 threads, 32 expf/iter — not 8192) into gbuf; stream broadcasts it.
// 3 barriers/iter at 2 blocks/CU (64 KiB ring); NT stores; barrier A waits
// vmcnt(32) so NT stores stay in flight, only stage loads drain.
#define SROWS 32
#define TC    256
#define NU    ((TC + WIN) / SROWS)   // 10 subtiles incl. 2 halo
#define NCHK  (TT / TC)              // 16 chunks per batch row

__global__ __launch_bounds__(256, 2) void fused_kernel(
        const float* __restrict__ x, const unsigned short* __restrict__ wpb,
        const float* __restrict__ bp, const float* __restrict__ Wg,
        float* __restrict__ out) {
    __shared__ __align__(16) float xs[2][SROWS * DD];   // 64 KiB ring
    __shared__ float gbuf[4][SROWS];                    // g ring (slot u&3)
    __shared__ __align__(16) float psv[SROWS][4];       // psum, [row][wave]
    const int tid  = threadIdx.x;
    const int lane = tid & 63;
    const int wave = tid >> 6;
    const int quad = lane >> 4;
    const int nrow = lane & 15;
    const int sw   = nrow & 7;          // row&7 == nrow&7 (mt*16 ≡ 0 mod 8)
    const int b     = blockIdx.x >> 4;          // NCHK = 16
    const int chunk = blockIdx.x & (NCHK - 1);
    const long t0   = (long)chunk * TC;
    const float* xb = x   + (size_t)b * TT * DD;
    float*       ob = out + (size_t)b * TT * DD;

    // B fragments: wave covers n in [wave*32, wave*32+32)
    bf16x8 bfrag[2][8];
    float bpv[2], wgv[2];
#pragma unroll
    for (int nt = 0; nt < 2; ++nt) {
        int n = wave * 32 + nt * 16 + nrow;
        bpv[nt] = bp[n];
        wgv[nt] = Wg[n];
#pragma unroll
        for (int k0 = 0; k0 < 8; ++k0)
            bfrag[nt][k0] = *reinterpret_cast<const bf16x8*>(
                wpb + n * DD + k0 * 32 + quad * 8);
    }

    // stage subtile su into ring slot su&1: 8 global_load_lds dwordx4 / wave.
    // LDS dest linear (row r, granule lane); global source granule lane^(r&7).
    auto stage = [&](int su) {
        const int nb = su & 1;
        const long r0 = t0 - WIN + (long)su * SROWS;
#pragma unroll
        for (int j = 0; j < 8; ++j) {
            int r = wave * 8 + j;
            long row = r0 + r;
            row = row < 0 ? 0 : row;          // t0=0 halo clamp (g=0 kills it)
            const float* gp = xb + row * DD + ((lane ^ (r & 7)) << 2);
            __builtin_amdgcn_global_load_lds(
                (const __attribute__((address_space(1))) void*)gp,
                (__attribute__((address_space(3))) void*)&xs[nb][r * DD],
                16, 0, 0);
        }
    };

    float hA[SROWS], hB[SROWS];   // cs history: 64 steps, parity-split, static idx
    float cs = 0.f, Sg = 0.f;

    stage(0);

    // stream body: broadcast g from gbuf + cs recurrence + windowed output.
    // H = parity-selected history array; all indices compile-time constants.
#define SBODY(H)                                                              \
    _Pragma("unroll")                                                         \
    for (int tt = 0; tt < SROWS; ++tt) {                                      \
        long t = rbase + tt;                                                  \
        float gnew = gbuf[u & 3][tt];         /* same-addr broadcast */       \
        int off = tt * DD + ((((tid >> 2) ^ (tt & 7)) << 2) | (tid & 3));     \
        cs += gnew * xt[off];                                                 \
        if (u >= 2) {                                                         \
            float gold = gbuf[(u + 2) & 3][tt];                               \
            Sg += gnew - gold;                                                \
            float h = H[tt];                                                  \
            H[tt] = cs;                                                       \
            float o = (cs - h) * __builtin_amdgcn_rcpf(Sg);                   \
            __builtin_nontemporal_store(o, &ob[t * DD + tid]);                \
        } else {                                                              \
            Sg += gnew;                                                       \
            H[tt] = cs;                                                       \
        }                                                                     \
    }

    for (int u = 0; u < NU; ++u) {
        // barrier A: stage(u) arrived (leave last iter's 32 NT stores in
        // flight); lgkmcnt(0) drains last iter's stream ds_reads of slot
        // (u+1)&1 so stage(u+1) may overwrite it.
        if (u >= 3) asm volatile("s_waitcnt vmcnt(32) lgkmcnt(0)" ::: "memory");
        else        asm volatile("s_waitcnt vmcnt(0) lgkmcnt(0)"  ::: "memory");
        __builtin_amdgcn_sched_barrier(0);
        __builtin_amdgcn_s_barrier();
        __builtin_amdgcn_sched_barrier(0);

        if (u + 1 < NU) stage(u + 1);        // prefetch, in flight all body

        // ---- gate MFMA on xs[u&1] ----
        const float* buf = xs[u & 1];
        f32x4 acc[2][2];
#pragma unroll
        for (int mt = 0; mt < 2; ++mt)
#pragma unroll
            for (int nt = 0; nt < 2; ++nt)
                acc[mt][nt] = (f32x4){0.f, 0.f, 0.f, 0.f};
#pragma unroll
        for (int k0 = 0; k0 < 8; ++k0) {
#pragma unroll
            for (int mt = 0; mt < 2; ++mt) {
                const float* rowp = buf + (mt * 16 + nrow) * DD;
                const int gidx = quad * 2 + k0 * 8;
                float4 f0 = *reinterpret_cast<const float4*>(rowp + (((gidx)     ^ sw) << 2));
                float4 f1 = *reinterpret_cast<const float4*>(rowp + (((gidx + 1) ^ sw) << 2));
                u32x4 w;
                w.x = cvt_pk_bf16(f0.x, f0.y);
                w.y = cvt_pk_bf16(f0.z, f0.w);
                w.z = cvt_pk_bf16(f1.x, f1.y);
                w.w = cvt_pk_bf16(f1.z, f1.w);
                bf16x8 af = __builtin_bit_cast(bf16x8, w);
                acc[mt][0] = __builtin_amdgcn_mfma_f32_16x16x32_bf16(af, bfrag[0][k0], acc[mt][0], 0, 0, 0);
                acc[mt][1] = __builtin_amdgcn_mfma_f32_16x16x32_bf16(af, bfrag[1][k0], acc[mt][1], 0, 0, 0);
            }
        }
        // epilogue: tanh -> *Wg -> partial row sums
        float p[2][4];
#pragma unroll
        for (int mt = 0; mt < 2; ++mt)
#pragma unroll
            for (int r = 0; r < 4; ++r) p[mt][r] = 0.f;
#pragma unroll
        for (int nt = 0; nt < 2; ++nt) {
#pragma unroll
            for (int mt = 0; mt < 2; ++mt) {
#pragma unroll
                for (int r = 0; r < 4; ++r) {
                    float pre = acc[mt][nt][r] + bpv[nt];
                    float e  = __expf(2.0f * pre);
                    float th = 1.0f - 2.0f * __builtin_amdgcn_rcpf(e + 1.0f);
                    p[mt][r] += th * wgv[nt];
                }
            }
        }
#pragma unroll
        for (int off = 1; off <= 8; off <<= 1)
#pragma unroll
            for (int mt = 0; mt < 2; ++mt)
#pragma unroll
                for (int r = 0; r < 4; ++r)
                    p[mt][r] += __shfl_xor(p[mt][r], off, 64);
        if (nrow == 0) {
#pragma unroll
            for (int mt = 0; mt < 2; ++mt)
#pragma unroll
                for (int r = 0; r < 4; ++r)
                    psv[mt * 16 + quad * 4 + r][wave] = p[mt][r];
        }

        asm volatile("s_waitcnt lgkmcnt(0)" ::: "memory");
        __builtin_amdgcn_sched_barrier(0);
        __builtin_amdgcn_s_barrier();        // barrier B: psv visible
        __builtin_amdgcn_sched_barrier(0);

        // ---- finalize g[u]: ONE expf per row (32 total) ----
        const long rbase = t0 - WIN + (long)u * SROWS;
        if (tid < SROWS) {
            f32x4 ps = *reinterpret_cast<const f32x4*>(&psv[tid][0]);
            float ss = (ps[0] + ps[1]) + (ps[2] + ps[3]);
            float gg = __builtin_amdgcn_rcpf(1.0f + __expf(-ss));
            gbuf[u & 3][tid] = (rbase + tid < 0) ? 0.f : gg;
        }

        asm volatile("s_waitcnt lgkmcnt(0)" ::: "memory");
        __builtin_amdgcn_sched_barrier(0);
        __builtin_amdgcn_s_barrier();        // barrier C: gbuf visible
        __builtin_amdgcn_sched_barrier(0);

        // ---- stream (lag-0): LDS x + register history + NT stores ----
        {
            const float* xt = xs[u & 1];
            if (u & 1) { SBODY(hB) } else { SBODY(hA) }
        }
    }
#undef SBODY
}

extern "C" void kernel_launch(void* const* d_in, const int* in_sizes, int n_in,
                              void* d_out, int out_size, void* d_ws, size_t ws_size,
                              hipStream_t stream) {
    const float* x  = (const float*)d_in[0];
    const float* Wp = (const float*)d_in[1];
    const float* bp = (const float*)d_in[2];
    const float* Wg = (const float*)d_in[3];
    float* out = (float*)d_out;

    // ws layout: [0,64K) Wp bf16
    unsigned short* wpb = (unsigned short*)d_ws;

    prep_wp<<<AA * DD / 256, 256, 0, stream>>>(Wp, wpb);
    fused_kernel<<<32 * NCHK, 256, 0, stream>>>(x, wpb, bp, Wg, out);
}